// Round 7
// baseline (78938.690 us; speedup 1.0000x reference)
//
#include <hip/hip_runtime.h>

#define LAT 64
#define ELLC 64       // ELL row capacity (deg ~ Poisson(32); overflow handled)
#define RB 128        // rows per bucket (128x64x4B = 32KB LDS ELL stage)
#define RBSH 7
#define MAXBUK 1024   // static LDS sizing; nbuk = ceil(N/128) = 782 for N=100k
#define NBLK 512      // bin_k blocks; (bucket,block) segment = CAPB dwords
#define CAPB 16       // 64B segment: one exclusive cache line per (bucket,block)

// fp8 (e4m3) y-state, per-layer scale s_k = SC0 * RSC^k (round-0 notes).
// x0 (dominant output term) bypasses fp8: qacc initialized from fp32 embeds.
// R6 post-mortem: build_k's LDS-staged ELL worked (55->~25us). bin_k (~45-60)
// now dominates preprocessing: 4 LDS atomics/edge + reservation pass + bbuf
// lines co-written by blocks on different XCDs (partial-line RMW ping-pong,
// the R5 disease in miniature). This round: FIXED-SEGMENT binning -- each
// (bucket,block) owns an exclusive 64B segment; 2 LDS atomics/edge, single
// pass, no reservations, no cross-block line sharing; build_k reads each
// bucket as one contiguous 32KB block + 2KB counts.
#define SC0 64.0f
#define RSC 3.0f

typedef float f32x2 __attribute__((ext_vector_type(2)));

// ---------- phase 1: fixed-segment bin (single pass over edges) ----------
// Packed word: (r & 127) << 17 | c   (needs N <= 131072).
__global__ void __launch_bounds__(1024)
bin_k(const int* __restrict__ eu, const int* __restrict__ ei,
      unsigned int* __restrict__ bbuf, int* __restrict__ cnt2d,
      int2* __restrict__ ovf, int* __restrict__ ovfc,
      int E, int U, int nbuk, int ovf_cap) {
    __shared__ int lbase[MAXBUK];
    for (int i = threadIdx.x; i < nbuk; i += blockDim.x) lbase[i] = 0;
    __syncthreads();
    int tid = blockIdx.x * blockDim.x + threadIdx.x;
    int stride = gridDim.x * blockDim.x;
    unsigned segbase = blockIdx.x * CAPB;
    for (int d = tid; d < E; d += stride) {
        int u = eu[d], c = ei[d] + U;
        int b = u >> RBSH;
        int pos = atomicAdd(&lbase[b], 1);
        if (pos < CAPB)
            bbuf[(size_t)b * (NBLK * CAPB) + segbase + pos] =
                ((unsigned)(u & (RB - 1)) << 17) | (unsigned)c;
        else { int o = atomicAdd(ovfc, 1); if (o < ovf_cap) ovf[o] = make_int2(u, c); }
        b = c >> RBSH;
        pos = atomicAdd(&lbase[b], 1);
        if (pos < CAPB)
            bbuf[(size_t)b * (NBLK * CAPB) + segbase + pos] =
                ((unsigned)(c & (RB - 1)) << 17) | (unsigned)u;
        else { int o = atomicAdd(ovfc, 1); if (o < ovf_cap) ovf[o] = make_int2(c, u); }
    }
    __syncthreads();
    for (int b = threadIdx.x; b < nbuk; b += blockDim.x)
        cnt2d[b * NBLK + blockIdx.x] = lbase[b];
}

// ---------- phase 2: per-bucket LDS-staged ELL + dinv + fused y0 (fp8) ------
// Bucket b's records live in one contiguous 32KB block of bbuf (512 segments
// x 64B); validity = slot < cnt2d[b][seg]. ELL staged in LDS (zero-init =
// free pad), streamed out as coalesced uint4.
__global__ void __launch_bounds__(1024)
build_k(const unsigned int* __restrict__ bbuf, const int* __restrict__ cnt2d,
        int* __restrict__ cnt, int* __restrict__ colE, float* __restrict__ dinv,
        const float* __restrict__ ue, const float* __restrict__ ie,
        unsigned char* __restrict__ y0,
        int2* __restrict__ rovf, int* __restrict__ rovfc,
        int N, int U, int rovf_cap) {
    __shared__ int lcnt[RB];
    __shared__ float ldv[RB];
    __shared__ int ell[RB * ELLC];   // 32KB
    __shared__ int scnt[NBLK];       // 2KB
    int b = blockIdx.x;
    for (int i = threadIdx.x; i < RB; i += blockDim.x) lcnt[i] = 0;
    for (int i = threadIdx.x; i < RB * ELLC; i += blockDim.x) ell[i] = 0;
    for (int i = threadIdx.x; i < NBLK; i += blockDim.x)
        scnt[i] = min(cnt2d[b * NBLK + i], CAPB);
    __syncthreads();
    const unsigned int* src = bbuf + (size_t)b * (NBLK * CAPB);
    for (int w = threadIdx.x; w < NBLK * CAPB; w += blockDim.x) {
        int seg = w >> 4;            // CAPB = 16
        int slot = w & (CAPB - 1);
        if (slot < scnt[seg]) {
            unsigned rec = src[w];
            int r7 = (int)(rec >> 17);
            int c = (int)(rec & 0x1FFFF);
            int pos = atomicAdd(&lcnt[r7], 1);
            if (pos < ELLC) ell[(r7 << 6) + pos] = c;
            else {
                int o = atomicAdd(rovfc, 1);
                if (o < rovf_cap) rovf[o] = make_int2((b << RBSH) + r7, c);
            }
        }
    }
    __syncthreads();
    for (int i = threadIdx.x; i < RB; i += blockDim.x) {
        int r = (b << RBSH) + i;
        if (r < N) {
            int d = lcnt[i];
            cnt[r] = d;
            float dv = (d > 0) ? rsqrtf((float)d) : 0.0f;
            dinv[r] = dv;            // spill rows fixed in fix_k
            ldv[i] = dv;
        }
    }
    __syncthreads();
    int r0 = b << RBSH;
    int rows = min(RB, N - r0);
    // fused y0 = fp8(SC0 * dinv * e0) for this bucket's rows (coalesced uint)
    for (int w = threadIdx.x; w < rows * 16; w += blockDim.x) {
        int i = w >> 4, j = w & 15;         // word j covers dims 4j..4j+3
        int r = r0 + i;
        const float* s = (r < U) ? (ue + (size_t)r * LAT) : (ie + (size_t)(r - U) * LAT);
        float4 f = ((const float4*)s)[j];
        float sc = SC0 * ldv[i];
        int p = __builtin_amdgcn_cvt_pk_fp8_f32(sc * f.x, sc * f.y, 0, false);
        p = __builtin_amdgcn_cvt_pk_fp8_f32(sc * f.z, sc * f.w, p, true);
        ((unsigned*)y0)[(size_t)r * 16 + j] = (unsigned)p;
    }
    // coalesced ELL writeout: rows*64 ints = rows*16 uint4 (pad included)
    uint4* dst = (uint4*)(colE + (size_t)r0 * ELLC);
    const uint4* lsrc = (const uint4*)ell;
    for (int w = threadIdx.x; w < rows * 16; w += blockDim.x)
        dst[w] = lsrc[w];
}

// bin-phase spill fix-up + dinv + y0 repair (~2-3k entries expected). Single
// block; __syncthreads between phases so final cnt is seen.
__global__ void __launch_bounds__(1024)
fix_k(const int2* __restrict__ ovf, const int* __restrict__ ovfc,
      int* __restrict__ cnt, int* __restrict__ colE, float* __restrict__ dinv,
      const float* __restrict__ ue, const float* __restrict__ ie,
      unsigned char* __restrict__ y0,
      int2* __restrict__ rovf, int* __restrict__ rovfc,
      int ovf_cap, int rovf_cap, int U) {
    int n = min(*ovfc, ovf_cap);
    for (int i = threadIdx.x; i < n; i += blockDim.x) {
        int r = ovf[i].x, c = ovf[i].y;
        int pos = atomicAdd(&cnt[r], 1);
        if (pos < ELLC) colE[(size_t)r * ELLC + pos] = c;
        else { int o = atomicAdd(rovfc, 1); if (o < rovf_cap) rovf[o] = make_int2(r, c); }
    }
    __syncthreads();
    for (int i = threadIdx.x; i < n; i += blockDim.x) {
        int r = ovf[i].x;
        int d = cnt[r];
        dinv[r] = (d > 0) ? rsqrtf((float)d) : 0.0f;
    }
    __syncthreads();
    for (int w = threadIdx.x; w < n * 16; w += blockDim.x) {
        int o = w >> 4, j = w & 15;
        int r = ovf[o].x;
        const float* s = (r < U) ? (ue + (size_t)r * LAT) : (ie + (size_t)(r - U) * LAT);
        float4 f = ((const float4*)s)[j];
        float sc = SC0 * dinv[r];
        int p = __builtin_amdgcn_cvt_pk_fp8_f32(sc * f.x, sc * f.y, 0, false);
        p = __builtin_amdgcn_cvt_pk_fp8_f32(sc * f.z, sc * f.w, p, true);
        ((unsigned*)y0)[(size_t)r * 16 + j] = (unsigned)p;
    }
}

// ---------- propagation core (unchanged from R4) ----------
// unpack one fp8 dword into 4 accumulator floats
__device__ __forceinline__ void acc_word(unsigned w, float* r) {
    f32x2 lo = __builtin_amdgcn_cvt_pk_f32_fp8((int)w, false);
    f32x2 hi = __builtin_amdgcn_cvt_pk_f32_fp8((int)w, true);
    r[0] += lo[0]; r[1] += lo[1]; r[2] += hi[0]; r[3] += hi[1];
}

// Row waves: 4 nodes/wave, one per 16-lane group. Lane decomposition within
// group: q = (lane>>2)&3 = neighbor slot (4 in flight), s4 = lane&3 = 16B
// chunk (dims 16*s4..16*s4+15). Cols preloaded TRANSPOSED: lane gl holds
// cols {gl, gl+16, gl+32, gl+48} -> step s (neighbors 4s..4s+3) needs one
// shfl from lane 4*(s&3)+q, compile-time component s>>2.
// Waves [NW, NW+2B): query gather (first: qacc = e0 exact fp32; else += x_k).
__global__ void __launch_bounds__(256, 4)
prop_h_k(const int* __restrict__ cnt, const int* __restrict__ colE,
         const float* __restrict__ dinv, const unsigned char* __restrict__ yin,
         unsigned char* __restrict__ yout,
         const int* __restrict__ users, const int* __restrict__ items,
         float* __restrict__ qacc,
         const float* __restrict__ ue, const float* __restrict__ ie,
         const int2* __restrict__ rovf, const int* __restrict__ rovfc,
         int rovf_cap, int B, int U, int first, int N, float inv_sin) {
    int wave = blockIdx.x * (blockDim.x >> 6) + (threadIdx.x >> 6);
    int lane = threadIdx.x & 63;
    int NW = (N + 3) >> 2;
    if (wave >= NW) {
        int qw = wave - NW;
        if (qw >= 2 * B) return;
        int node = (qw < B) ? users[qw] : (items[qw - B] + U);
        if (first) {
            float v = (node < U) ? ue[(size_t)node * LAT + lane]
                                 : ie[(size_t)(node - U) * LAT + lane];
            qacc[qw * LAT + lane] = v;
        } else {
            float di = dinv[node];
            unsigned bb = yin[(size_t)node * LAT + lane];      // one 64B line/wave
            f32x2 yv = __builtin_amdgcn_cvt_pk_f32_fp8((int)bb, false);
            qacc[qw * LAT + lane] += (di > 0.0f) ? yv[0] * inv_sin / di : 0.0f;
        }
        return;
    }
    int grp  = lane >> 4;          // group 0..3 -> node
    int gbase = lane & 48;         // grp*16
    int q  = (lane >> 2) & 3;      // neighbor slot within step
    int s4 = lane & 3;             // 16B chunk: dims 16*s4..16*s4+15
    int node = (wave << 2) + grp;
    int nadr = min(node, N - 1);   // clamped address for tail groups
    int len = (node < N) ? min(cnt[nadr], ELLC) : 0;
    const int* cp = colE + (size_t)nadr * ELLC;
    // transposed col registers: lane gl holds cols gl+16c (4 coalesced loads)
    int gl = lane & 15;
    int ca0 = cp[gl], ca1 = cp[16 + gl], ca2 = cp[32 + gl], ca3 = cp[48 + gl];
    // wave-uniform step bound (max len over the 4 groups)
    int wmax = len;
    wmax = max(wmax, __shfl_xor(wmax, 16));
    wmax = max(wmax, __shfl_xor(wmax, 32));
    wmax = __builtin_amdgcn_readfirstlane(wmax);
    const uint4* y16 = (const uint4*)yin;

    float r[16];
#pragma unroll
    for (int j = 0; j < 16; ++j) r[j] = 0.f;

#pragma unroll
    for (int c = 0; c < 4; ++c) {
        int cac = (c == 0) ? ca0 : (c == 1) ? ca1 : (c == 2) ? ca2 : ca3;
#pragma unroll
        for (int si = 0; si < 4; ++si) {
            int s = (c << 2) + si;
            if ((s << 2) < wmax) {                 // wave-uniform guard
                int col = __shfl(cac, gbase + (si << 2) + q);   // 1 shfl / 4 nbrs
                if ((s << 2) + q < len) {          // per-lane validity
                    uint4 v = y16[(size_t)col * 4 + s4];
                    acc_word(v.x, r + 0); acc_word(v.y, r + 4);
                    acc_word(v.z, r + 8); acc_word(v.w, r + 12);
                }
            }
        }
    }
    // inline overflow epilogue (rovf static across layers; expected empty):
    // q==0 lanes (s4 = 0..3) cover the full row; reduce sums it in.
    int novf = min(*rovfc, rovf_cap);
    for (int o = 0; o < novf; ++o) {
        int2 eo = rovf[o];
        if (eo.x == node && q == 0) {
            uint4 vv = y16[(size_t)eo.y * 4 + s4];
            acc_word(vv.x, r + 0); acc_word(vv.y, r + 4);
            acc_word(vv.z, r + 8); acc_word(vv.w, r + 12);
        }
    }
    // reduce-scatter across q (12 shfl): stage A xor4 (q bit0), keep 8 dims;
    // stage B xor8 (q bit1), keep 4. Lane ends with dims d0..d0+3 fully
    // summed, d0 = 16*s4 + 8*b2 + 4*b3.
    {
        bool hi = (lane & 4) != 0;
        float s8[8], k8[8];
#pragma unroll
        for (int i = 0; i < 8; ++i) { k8[i] = hi ? r[8 + i] : r[i]; s8[i] = hi ? r[i] : r[8 + i]; }
#pragma unroll
        for (int i = 0; i < 8; ++i) r[i] = k8[i] + __shfl_xor(s8[i], 4);
    }
    {
        bool hi = (lane & 8) != 0;
        float s4a[4], k4a[4];
#pragma unroll
        for (int i = 0; i < 4; ++i) { k4a[i] = hi ? r[4 + i] : r[i]; s4a[i] = hi ? r[i] : r[4 + i]; }
#pragma unroll
        for (int i = 0; i < 4; ++i) r[i] = k4a[i] + __shfl_xor(s4a[i], 8);
    }
    // zero-shuffle pack + store: lane packs its 4 dims into 1 dword; 64 lanes
    // store 4 nodes x 64B coalesced.
    float dv = dinv[nadr];
    float f = dv * dv * RSC;               // fold out/in scale ratio into dinv^2
    int pk = __builtin_amdgcn_cvt_pk_fp8_f32(f * r[0], f * r[1], 0, false);
    pk = __builtin_amdgcn_cvt_pk_fp8_f32(f * r[2], f * r[3], pk, true);
    if (node < N) {
        int b2 = (lane >> 2) & 1, b3 = (lane >> 3) & 1;
        ((unsigned*)yout)[(size_t)node * 16 + (s4 << 2) + (b2 << 1) + b3] = (unsigned)pk;
    }
}

// final: qacc += x4 at queried nodes, then gamma = dot/25 (fused last qgather)
__global__ void final_k(const float* __restrict__ qacc, const unsigned char* __restrict__ y4,
                        const float* __restrict__ dinv,
                        const int* __restrict__ users, const int* __restrict__ items,
                        float* __restrict__ out, int B, int U, float inv_s4) {
    int wave = blockIdx.x * (blockDim.x >> 6) + (threadIdx.x >> 6);
    int lane = threadIdx.x & 63;
    if (wave >= B) return;
    int un = users[wave];
    int in = items[wave] + U;
    float du = dinv[un], di = dinv[in];
    unsigned bu = y4[(size_t)un * LAT + lane];
    unsigned bi = y4[(size_t)in * LAT + lane];
    f32x2 xuv = __builtin_amdgcn_cvt_pk_f32_fp8((int)bu, false);
    f32x2 xiv = __builtin_amdgcn_cvt_pk_f32_fp8((int)bi, false);
    float au = qacc[wave * LAT + lane]       + ((du > 0.f) ? xuv[0] * inv_s4 / du : 0.f);
    float ai = qacc[(wave + B) * LAT + lane] + ((di > 0.f) ? xiv[0] * inv_s4 / di : 0.f);
    float p = au * ai;
#pragma unroll
    for (int off = 32; off > 0; off >>= 1) p += __shfl_down(p, off);
    if (lane == 0) out[wave] = p * (1.0f / 25.0f);
}

extern "C" void kernel_launch(void* const* d_in, const int* in_sizes, int n_in,
                              void* d_out, int out_size, void* d_ws, size_t ws_size,
                              hipStream_t stream) {
    const float* ue = (const float*)d_in[0];
    const float* ie = (const float*)d_in[1];
    const int* edge = (const int*)d_in[2];
    const int* users = (const int*)d_in[3];
    const int* items = (const int*)d_in[4];

    const int U = in_sizes[0] / LAT;
    const int I = in_sizes[1] / LAT;
    const int N = U + I;
    const int E = in_sizes[2] / 2;
    const int B = in_sizes[3];
    const int* eu = edge;
    const int* ei = edge + E;

    const int nbuk = (N + RB - 1) / RB;                    // 782 for N=100k

    char* ws = (char*)d_ws;
    size_t off = 0;
    auto alloc = [&](size_t bytes) -> void* {
        void* p = ws + off;
        off += (bytes + 255) & ~(size_t)255;
        return p;
    };
    int*           cnt  = (int*)alloc((size_t)4 * N);
    float*         dinv = (float*)alloc((size_t)4 * N);
    int*           colE = (int*)alloc((size_t)4 * N * ELLC);     // 25.6 MB
    unsigned char* yA   = (unsigned char*)alloc((size_t)N * LAT); // 6.4 MB fp8
    unsigned char* yB   = (unsigned char*)alloc((size_t)N * LAT);
    float*         qacc = (float*)alloc((size_t)4 * 2 * B * LAT);
    unsigned*      bbuf = (unsigned*)alloc((size_t)4 * nbuk * NBLK * CAPB); // 25.6 MB
    int*           cnt2d = (int*)alloc((size_t)4 * nbuk * NBLK); // 1.6 MB
    int*           ovfc  = (int*)alloc(256);   // [0]=bin spill, [64]=row ovf
    size_t remain = (ws_size > off + 256) ? (ws_size - off - 256) : 0;
    int ovf_cap = (int)min((size_t)131072, remain / (2 * sizeof(int2)));
    int2* ovf  = (int2*)alloc((size_t)ovf_cap * sizeof(int2));
    int2* rovf = (int2*)alloc((size_t)ovf_cap * sizeof(int2));
    int* rovfc = ovfc + 64;

    hipError_t _e = hipMemsetAsync(ovfc, 0, 256, stream); (void)_e;

    const int tb = 256;

    bin_k<<<NBLK, 1024, 0, stream>>>(eu, ei, bbuf, cnt2d, ovf, ovfc, E, U, nbuk, ovf_cap);
    build_k<<<nbuk, 1024, 0, stream>>>(bbuf, cnt2d, cnt, colE, dinv, ue, ie, yA,
                                       rovf, rovfc, N, U, ovf_cap);
    fix_k<<<1, 1024, 0, stream>>>(ovf, ovfc, cnt, colE, dinv, ue, ie, yA,
                                  rovf, rovfc, ovf_cap, ovf_cap, U);

    const int wpb = tb / 64;
    const int NW = (N + 3) >> 2;               // 4 nodes per row-wave
    int pgrid = (NW + 2 * B + wpb - 1) / wpb;  // row waves + fused query waves

    unsigned char* yin = yA;
    unsigned char* yout = yB;
    float s_in = SC0;
    for (int layer = 0; layer < 4; ++layer) {
        prop_h_k<<<pgrid, tb, 0, stream>>>(cnt, colE, dinv, yin, yout,
                                           users, items, qacc, ue, ie, rovf, rovfc,
                                           ovf_cap, B, U, layer == 0 ? 1 : 0, N,
                                           1.0f / s_in);
        s_in *= RSC;
        unsigned char* tmp = yin; yin = yout; yout = tmp;
    }

    final_k<<<(B + wpb - 1) / wpb, tb, 0, stream>>>(qacc, yin, dinv, users, items,
                                                    (float*)d_out, B, U, 1.0f / s_in);
}

// Round 8
// 308.766 us; speedup vs baseline: 255.6583x; 255.6583x over previous
//
#include <hip/hip_runtime.h>

#define LAT 64
#define ELLC 64       // ELL row capacity (deg ~ Poisson(32); overflow handled)
#define RB 128        // rows per bucket (128x64x4B = 32KB LDS ELL stage)
#define RBSH 7
#define MAXBUK 1024   // static LDS sizing; nbuk = ceil(N/128) = 782 for N=100k
#define NBLK 512      // bin_k blocks; (bucket,block) segment = CAPB dwords
#define CAPB 16       // 64B segment: one exclusive cache line per (bucket,block)

// fp8 (e4m3) y-state, per-layer scale s_k = SC0 * RSC^k (round-0 notes).
// x0 (dominant output term) bypasses fp8: qacc initialized from fp32 embeds.
// R7 post-mortem: 34.7ms prop was a latent OOB -- rovfc = ovfc + 64 INTS =
// byte 256 = first bytes of ovf[0] (alloc(256) = 256 BYTES = 64 ints).
// R7's bin spills wrote ovf[0].x = node id -> *rovfc ~25k -> prop's rovf
// epilogue looped 25k times/wave. Fix: rovfc = ovfc + 16 (byte 64, inside
// the zeroed 256B block). Fixed-segment binning itself unchanged/unmeasured.
#define SC0 64.0f
#define RSC 3.0f

typedef float f32x2 __attribute__((ext_vector_type(2)));

// ---------- phase 1: fixed-segment bin (single pass over edges) ----------
// Packed word: (r & 127) << 17 | c   (needs N <= 131072).
__global__ void __launch_bounds__(1024)
bin_k(const int* __restrict__ eu, const int* __restrict__ ei,
      unsigned int* __restrict__ bbuf, int* __restrict__ cnt2d,
      int2* __restrict__ ovf, int* __restrict__ ovfc,
      int E, int U, int nbuk, int ovf_cap) {
    __shared__ int lbase[MAXBUK];
    for (int i = threadIdx.x; i < nbuk; i += blockDim.x) lbase[i] = 0;
    __syncthreads();
    int tid = blockIdx.x * blockDim.x + threadIdx.x;
    int stride = gridDim.x * blockDim.x;
    unsigned segbase = blockIdx.x * CAPB;
    for (int d = tid; d < E; d += stride) {
        int u = eu[d], c = ei[d] + U;
        int b = u >> RBSH;
        int pos = atomicAdd(&lbase[b], 1);
        if (pos < CAPB)
            bbuf[(size_t)b * (NBLK * CAPB) + segbase + pos] =
                ((unsigned)(u & (RB - 1)) << 17) | (unsigned)c;
        else { int o = atomicAdd(ovfc, 1); if (o < ovf_cap) ovf[o] = make_int2(u, c); }
        b = c >> RBSH;
        pos = atomicAdd(&lbase[b], 1);
        if (pos < CAPB)
            bbuf[(size_t)b * (NBLK * CAPB) + segbase + pos] =
                ((unsigned)(c & (RB - 1)) << 17) | (unsigned)u;
        else { int o = atomicAdd(ovfc, 1); if (o < ovf_cap) ovf[o] = make_int2(c, u); }
    }
    __syncthreads();
    for (int b = threadIdx.x; b < nbuk; b += blockDim.x)
        cnt2d[b * NBLK + blockIdx.x] = lbase[b];
}

// ---------- phase 2: per-bucket LDS-staged ELL + dinv + fused y0 (fp8) ------
// Bucket b's records live in one contiguous 32KB block of bbuf (512 segments
// x 64B); validity = slot < cnt2d[b][seg]. ELL staged in LDS (zero-init =
// free pad), streamed out as coalesced uint4.
__global__ void __launch_bounds__(1024)
build_k(const unsigned int* __restrict__ bbuf, const int* __restrict__ cnt2d,
        int* __restrict__ cnt, int* __restrict__ colE, float* __restrict__ dinv,
        const float* __restrict__ ue, const float* __restrict__ ie,
        unsigned char* __restrict__ y0,
        int2* __restrict__ rovf, int* __restrict__ rovfc,
        int N, int U, int rovf_cap) {
    __shared__ int lcnt[RB];
    __shared__ float ldv[RB];
    __shared__ int ell[RB * ELLC];   // 32KB
    __shared__ int scnt[NBLK];       // 2KB
    int b = blockIdx.x;
    for (int i = threadIdx.x; i < RB; i += blockDim.x) lcnt[i] = 0;
    for (int i = threadIdx.x; i < RB * ELLC; i += blockDim.x) ell[i] = 0;
    for (int i = threadIdx.x; i < NBLK; i += blockDim.x)
        scnt[i] = min(cnt2d[b * NBLK + i], CAPB);
    __syncthreads();
    const unsigned int* src = bbuf + (size_t)b * (NBLK * CAPB);
    for (int w = threadIdx.x; w < NBLK * CAPB; w += blockDim.x) {
        int seg = w >> 4;            // CAPB = 16
        int slot = w & (CAPB - 1);
        if (slot < scnt[seg]) {
            unsigned rec = src[w];
            int r7 = (int)(rec >> 17);
            int c = (int)(rec & 0x1FFFF);
            int pos = atomicAdd(&lcnt[r7], 1);
            if (pos < ELLC) ell[(r7 << 6) + pos] = c;
            else {
                int o = atomicAdd(rovfc, 1);
                if (o < rovf_cap) rovf[o] = make_int2((b << RBSH) + r7, c);
            }
        }
    }
    __syncthreads();
    for (int i = threadIdx.x; i < RB; i += blockDim.x) {
        int r = (b << RBSH) + i;
        if (r < N) {
            int d = lcnt[i];
            cnt[r] = d;
            float dv = (d > 0) ? rsqrtf((float)d) : 0.0f;
            dinv[r] = dv;            // spill rows fixed in fix_k
            ldv[i] = dv;
        }
    }
    __syncthreads();
    int r0 = b << RBSH;
    int rows = min(RB, N - r0);
    // fused y0 = fp8(SC0 * dinv * e0) for this bucket's rows (coalesced uint)
    for (int w = threadIdx.x; w < rows * 16; w += blockDim.x) {
        int i = w >> 4, j = w & 15;         // word j covers dims 4j..4j+3
        int r = r0 + i;
        const float* s = (r < U) ? (ue + (size_t)r * LAT) : (ie + (size_t)(r - U) * LAT);
        float4 f = ((const float4*)s)[j];
        float sc = SC0 * ldv[i];
        int p = __builtin_amdgcn_cvt_pk_fp8_f32(sc * f.x, sc * f.y, 0, false);
        p = __builtin_amdgcn_cvt_pk_fp8_f32(sc * f.z, sc * f.w, p, true);
        ((unsigned*)y0)[(size_t)r * 16 + j] = (unsigned)p;
    }
    // coalesced ELL writeout: rows*64 ints = rows*16 uint4 (pad included)
    uint4* dst = (uint4*)(colE + (size_t)r0 * ELLC);
    const uint4* lsrc = (const uint4*)ell;
    for (int w = threadIdx.x; w < rows * 16; w += blockDim.x)
        dst[w] = lsrc[w];
}

// bin-phase spill fix-up + dinv + y0 repair (~5k entries expected). Single
// block; __syncthreads between phases so final cnt is seen.
__global__ void __launch_bounds__(1024)
fix_k(const int2* __restrict__ ovf, const int* __restrict__ ovfc,
      int* __restrict__ cnt, int* __restrict__ colE, float* __restrict__ dinv,
      const float* __restrict__ ue, const float* __restrict__ ie,
      unsigned char* __restrict__ y0,
      int2* __restrict__ rovf, int* __restrict__ rovfc,
      int ovf_cap, int rovf_cap, int U) {
    int n = min(*ovfc, ovf_cap);
    for (int i = threadIdx.x; i < n; i += blockDim.x) {
        int r = ovf[i].x, c = ovf[i].y;
        int pos = atomicAdd(&cnt[r], 1);
        if (pos < ELLC) colE[(size_t)r * ELLC + pos] = c;
        else { int o = atomicAdd(rovfc, 1); if (o < rovf_cap) rovf[o] = make_int2(r, c); }
    }
    __syncthreads();
    for (int i = threadIdx.x; i < n; i += blockDim.x) {
        int r = ovf[i].x;
        int d = cnt[r];
        dinv[r] = (d > 0) ? rsqrtf((float)d) : 0.0f;
    }
    __syncthreads();
    for (int w = threadIdx.x; w < n * 16; w += blockDim.x) {
        int o = w >> 4, j = w & 15;
        int r = ovf[o].x;
        const float* s = (r < U) ? (ue + (size_t)r * LAT) : (ie + (size_t)(r - U) * LAT);
        float4 f = ((const float4*)s)[j];
        float sc = SC0 * dinv[r];
        int p = __builtin_amdgcn_cvt_pk_fp8_f32(sc * f.x, sc * f.y, 0, false);
        p = __builtin_amdgcn_cvt_pk_fp8_f32(sc * f.z, sc * f.w, p, true);
        ((unsigned*)y0)[(size_t)r * 16 + j] = (unsigned)p;
    }
}

// ---------- propagation core (unchanged from R4) ----------
// unpack one fp8 dword into 4 accumulator floats
__device__ __forceinline__ void acc_word(unsigned w, float* r) {
    f32x2 lo = __builtin_amdgcn_cvt_pk_f32_fp8((int)w, false);
    f32x2 hi = __builtin_amdgcn_cvt_pk_f32_fp8((int)w, true);
    r[0] += lo[0]; r[1] += lo[1]; r[2] += hi[0]; r[3] += hi[1];
}

// Row waves: 4 nodes/wave, one per 16-lane group. Lane decomposition within
// group: q = (lane>>2)&3 = neighbor slot (4 in flight), s4 = lane&3 = 16B
// chunk (dims 16*s4..16*s4+15). Cols preloaded TRANSPOSED: lane gl holds
// cols {gl, gl+16, gl+32, gl+48} -> step s (neighbors 4s..4s+3) needs one
// shfl from lane 4*(s&3)+q, compile-time component s>>2.
// Waves [NW, NW+2B): query gather (first: qacc = e0 exact fp32; else += x_k).
__global__ void __launch_bounds__(256, 4)
prop_h_k(const int* __restrict__ cnt, const int* __restrict__ colE,
         const float* __restrict__ dinv, const unsigned char* __restrict__ yin,
         unsigned char* __restrict__ yout,
         const int* __restrict__ users, const int* __restrict__ items,
         float* __restrict__ qacc,
         const float* __restrict__ ue, const float* __restrict__ ie,
         const int2* __restrict__ rovf, const int* __restrict__ rovfc,
         int rovf_cap, int B, int U, int first, int N, float inv_sin) {
    int wave = blockIdx.x * (blockDim.x >> 6) + (threadIdx.x >> 6);
    int lane = threadIdx.x & 63;
    int NW = (N + 3) >> 2;
    if (wave >= NW) {
        int qw = wave - NW;
        if (qw >= 2 * B) return;
        int node = (qw < B) ? users[qw] : (items[qw - B] + U);
        if (first) {
            float v = (node < U) ? ue[(size_t)node * LAT + lane]
                                 : ie[(size_t)(node - U) * LAT + lane];
            qacc[qw * LAT + lane] = v;
        } else {
            float di = dinv[node];
            unsigned bb = yin[(size_t)node * LAT + lane];      // one 64B line/wave
            f32x2 yv = __builtin_amdgcn_cvt_pk_f32_fp8((int)bb, false);
            qacc[qw * LAT + lane] += (di > 0.0f) ? yv[0] * inv_sin / di : 0.0f;
        }
        return;
    }
    int grp  = lane >> 4;          // group 0..3 -> node
    int gbase = lane & 48;         // grp*16
    int q  = (lane >> 2) & 3;      // neighbor slot within step
    int s4 = lane & 3;             // 16B chunk: dims 16*s4..16*s4+15
    int node = (wave << 2) + grp;
    int nadr = min(node, N - 1);   // clamped address for tail groups
    int len = (node < N) ? min(cnt[nadr], ELLC) : 0;
    const int* cp = colE + (size_t)nadr * ELLC;
    // transposed col registers: lane gl holds cols gl+16c (4 coalesced loads)
    int gl = lane & 15;
    int ca0 = cp[gl], ca1 = cp[16 + gl], ca2 = cp[32 + gl], ca3 = cp[48 + gl];
    // wave-uniform step bound (max len over the 4 groups)
    int wmax = len;
    wmax = max(wmax, __shfl_xor(wmax, 16));
    wmax = max(wmax, __shfl_xor(wmax, 32));
    wmax = __builtin_amdgcn_readfirstlane(wmax);
    const uint4* y16 = (const uint4*)yin;

    float r[16];
#pragma unroll
    for (int j = 0; j < 16; ++j) r[j] = 0.f;

#pragma unroll
    for (int c = 0; c < 4; ++c) {
        int cac = (c == 0) ? ca0 : (c == 1) ? ca1 : (c == 2) ? ca2 : ca3;
#pragma unroll
        for (int si = 0; si < 4; ++si) {
            int s = (c << 2) + si;
            if ((s << 2) < wmax) {                 // wave-uniform guard
                int col = __shfl(cac, gbase + (si << 2) + q);   // 1 shfl / 4 nbrs
                if ((s << 2) + q < len) {          // per-lane validity
                    uint4 v = y16[(size_t)col * 4 + s4];
                    acc_word(v.x, r + 0); acc_word(v.y, r + 4);
                    acc_word(v.z, r + 8); acc_word(v.w, r + 12);
                }
            }
        }
    }
    // inline overflow epilogue (rovf static across layers; expected ~0):
    // q==0 lanes (s4 = 0..3) cover the full row; reduce sums it in.
    int novf = min(*rovfc, rovf_cap);
    for (int o = 0; o < novf; ++o) {
        int2 eo = rovf[o];
        if (eo.x == node && q == 0) {
            uint4 vv = y16[(size_t)eo.y * 4 + s4];
            acc_word(vv.x, r + 0); acc_word(vv.y, r + 4);
            acc_word(vv.z, r + 8); acc_word(vv.w, r + 12);
        }
    }
    // reduce-scatter across q (12 shfl): stage A xor4 (q bit0), keep 8 dims;
    // stage B xor8 (q bit1), keep 4. Lane ends with dims d0..d0+3 fully
    // summed, d0 = 16*s4 + 8*b2 + 4*b3.
    {
        bool hi = (lane & 4) != 0;
        float s8[8], k8[8];
#pragma unroll
        for (int i = 0; i < 8; ++i) { k8[i] = hi ? r[8 + i] : r[i]; s8[i] = hi ? r[i] : r[8 + i]; }
#pragma unroll
        for (int i = 0; i < 8; ++i) r[i] = k8[i] + __shfl_xor(s8[i], 4);
    }
    {
        bool hi = (lane & 8) != 0;
        float s4a[4], k4a[4];
#pragma unroll
        for (int i = 0; i < 4; ++i) { k4a[i] = hi ? r[4 + i] : r[i]; s4a[i] = hi ? r[i] : r[4 + i]; }
#pragma unroll
        for (int i = 0; i < 4; ++i) r[i] = k4a[i] + __shfl_xor(s4a[i], 8);
    }
    // zero-shuffle pack + store: lane packs its 4 dims into 1 dword; 64 lanes
    // store 4 nodes x 64B coalesced.
    float dv = dinv[nadr];
    float f = dv * dv * RSC;               // fold out/in scale ratio into dinv^2
    int pk = __builtin_amdgcn_cvt_pk_fp8_f32(f * r[0], f * r[1], 0, false);
    pk = __builtin_amdgcn_cvt_pk_fp8_f32(f * r[2], f * r[3], pk, true);
    if (node < N) {
        int b2 = (lane >> 2) & 1, b3 = (lane >> 3) & 1;
        ((unsigned*)yout)[(size_t)node * 16 + (s4 << 2) + (b2 << 1) + b3] = (unsigned)pk;
    }
}

// final: qacc += x4 at queried nodes, then gamma = dot/25 (fused last qgather)
__global__ void final_k(const float* __restrict__ qacc, const unsigned char* __restrict__ y4,
                        const float* __restrict__ dinv,
                        const int* __restrict__ users, const int* __restrict__ items,
                        float* __restrict__ out, int B, int U, float inv_s4) {
    int wave = blockIdx.x * (blockDim.x >> 6) + (threadIdx.x >> 6);
    int lane = threadIdx.x & 63;
    if (wave >= B) return;
    int un = users[wave];
    int in = items[wave] + U;
    float du = dinv[un], di = dinv[in];
    unsigned bu = y4[(size_t)un * LAT + lane];
    unsigned bi = y4[(size_t)in * LAT + lane];
    f32x2 xuv = __builtin_amdgcn_cvt_pk_f32_fp8((int)bu, false);
    f32x2 xiv = __builtin_amdgcn_cvt_pk_f32_fp8((int)bi, false);
    float au = qacc[wave * LAT + lane]       + ((du > 0.f) ? xuv[0] * inv_s4 / du : 0.f);
    float ai = qacc[(wave + B) * LAT + lane] + ((di > 0.f) ? xiv[0] * inv_s4 / di : 0.f);
    float p = au * ai;
#pragma unroll
    for (int off = 32; off > 0; off >>= 1) p += __shfl_down(p, off);
    if (lane == 0) out[wave] = p * (1.0f / 25.0f);
}

extern "C" void kernel_launch(void* const* d_in, const int* in_sizes, int n_in,
                              void* d_out, int out_size, void* d_ws, size_t ws_size,
                              hipStream_t stream) {
    const float* ue = (const float*)d_in[0];
    const float* ie = (const float*)d_in[1];
    const int* edge = (const int*)d_in[2];
    const int* users = (const int*)d_in[3];
    const int* items = (const int*)d_in[4];

    const int U = in_sizes[0] / LAT;
    const int I = in_sizes[1] / LAT;
    const int N = U + I;
    const int E = in_sizes[2] / 2;
    const int B = in_sizes[3];
    const int* eu = edge;
    const int* ei = edge + E;

    const int nbuk = (N + RB - 1) / RB;                    // 782 for N=100k

    char* ws = (char*)d_ws;
    size_t off = 0;
    auto alloc = [&](size_t bytes) -> void* {
        void* p = ws + off;
        off += (bytes + 255) & ~(size_t)255;
        return p;
    };
    int*           cnt  = (int*)alloc((size_t)4 * N);
    float*         dinv = (float*)alloc((size_t)4 * N);
    int*           colE = (int*)alloc((size_t)4 * N * ELLC);     // 25.6 MB
    unsigned char* yA   = (unsigned char*)alloc((size_t)N * LAT); // 6.4 MB fp8
    unsigned char* yB   = (unsigned char*)alloc((size_t)N * LAT);
    float*         qacc = (float*)alloc((size_t)4 * 2 * B * LAT);
    unsigned*      bbuf = (unsigned*)alloc((size_t)4 * nbuk * NBLK * CAPB); // 25.6 MB
    int*           cnt2d = (int*)alloc((size_t)4 * nbuk * NBLK); // 1.6 MB
    int*           ovfc  = (int*)alloc(256);   // 64 ints: [0]=bin spill, [16]=row ovf
    size_t remain = (ws_size > off + 256) ? (ws_size - off - 256) : 0;
    int ovf_cap = (int)min((size_t)131072, remain / (2 * sizeof(int2)));
    int2* ovf  = (int2*)alloc((size_t)ovf_cap * sizeof(int2));
    int2* rovf = (int2*)alloc((size_t)ovf_cap * sizeof(int2));
    // R7 BUG FIX: was ovfc + 64 (= byte 256, OOB into ovf[0] -- bin spills
    // overwrote the row-ovf counter with node ids -> prop looped 25k times).
    // Byte offset 64 stays inside the 256-byte zeroed allocation.
    int* rovfc = ovfc + 16;

    hipError_t _e = hipMemsetAsync(ovfc, 0, 256, stream); (void)_e;

    const int tb = 256;

    bin_k<<<NBLK, 1024, 0, stream>>>(eu, ei, bbuf, cnt2d, ovf, ovfc, E, U, nbuk, ovf_cap);
    build_k<<<nbuk, 1024, 0, stream>>>(bbuf, cnt2d, cnt, colE, dinv, ue, ie, yA,
                                       rovf, rovfc, N, U, ovf_cap);
    fix_k<<<1, 1024, 0, stream>>>(ovf, ovfc, cnt, colE, dinv, ue, ie, yA,
                                  rovf, rovfc, ovf_cap, ovf_cap, U);

    const int wpb = tb / 64;
    const int NW = (N + 3) >> 2;               // 4 nodes per row-wave
    int pgrid = (NW + 2 * B + wpb - 1) / wpb;  // row waves + fused query waves

    unsigned char* yin = yA;
    unsigned char* yout = yB;
    float s_in = SC0;
    for (int layer = 0; layer < 4; ++layer) {
        prop_h_k<<<pgrid, tb, 0, stream>>>(cnt, colE, dinv, yin, yout,
                                           users, items, qacc, ue, ie, rovf, rovfc,
                                           ovf_cap, B, U, layer == 0 ? 1 : 0, N,
                                           1.0f / s_in);
        s_in *= RSC;
        unsigned char* tmp = yin; yin = yout; yout = tmp;
    }

    final_k<<<(B + wpb - 1) / wpb, tb, 0, stream>>>(qacc, yin, dinv, users, items,
                                                    (float*)d_out, B, U, 1.0f / s_in);
}

// Round 10
// 238.181 us; speedup vs baseline: 331.4232x; 1.2964x over previous
//
#include <hip/hip_runtime.h>

#define LAT 64
#define ELLC 64       // ELL row capacity (deg ~ Poisson(32); overflow handled)
#define RB 128        // rows per bucket (128x64x4B = 32KB LDS ELL stage)
#define RBSH 7
#define MAXBUK 1024   // static LDS sizing; nbuk = ceil(N/128) = 782 for N=100k
#define RPT 8         // undirected edges cached per thread (256 x 1024 x 8 >= E)

// fp8 (e4m3) y-state, per-layer scale s_k = SC0 * RSC^k (round-0 notes).
// x0 (dominant output term) bypasses fp8: qacc initialized from fp32 embeds.
// R8 post-mortem: fixed-segment binning falsified (62us bin: 3x write amp --
// segments fill in ~8 bursts, lines evicted between bursts; 59us fix_k: 8.5k
// spills through ONE CU). Reverted to R6's reservation binning (dense bucket
// regions, ~0 spills), WITH the rovfc OOB fix (ovfc+64 ints aliased ovf[0];
// R6 passed only because its spill count was 0). Prop: accumulate in f32x2
// pairs -> v_pk_add_f32 (half the accumulate adds).
#define SC0 64.0f
#define RSC 3.0f

typedef float f32x2 __attribute__((ext_vector_type(2)));

// ---------- phase 1: bin directed edges by row-bucket (single edge read) -----
// Packed word: (r & 127) << 17 | c   (needs N <= 131072).
__global__ void __launch_bounds__(1024)
bin_k(const int* __restrict__ eu, const int* __restrict__ ei,
      int* __restrict__ gcur, unsigned int* __restrict__ bbuf,
      int2* __restrict__ ovf, int* __restrict__ ovfc,
      int E, int U, int nbuk, int cap, int ovf_cap) {
    __shared__ int lcnt[MAXBUK];
    __shared__ int lbase[MAXBUK];
    for (int i = threadIdx.x; i < nbuk; i += blockDim.x) lcnt[i] = 0;
    __syncthreads();
    int tid = blockIdx.x * blockDim.x + threadIdx.x;
    int stride = gridDim.x * blockDim.x;
    int ru[RPT], rc[RPT];
    int ne = 0;
#pragma unroll
    for (int k = 0; k < RPT; ++k) {
        int d = tid + k * stride;
        if (d < E) {
            int u = eu[d], c = ei[d] + U;
            ru[k] = u; rc[k] = c; ne = k + 1;
            atomicAdd(&lcnt[u >> RBSH], 1);   // user-side row
            atomicAdd(&lcnt[c >> RBSH], 1);   // item-side row
        }
    }
    __syncthreads();
    for (int b = threadIdx.x; b < nbuk; b += blockDim.x)
        lbase[b] = atomicAdd(&gcur[b], lcnt[b]);      // global reservation
    __syncthreads();
#pragma unroll
    for (int k = 0; k < RPT; ++k) {
        if (k < ne) {
            int u = ru[k], c = rc[k];
            int b = u >> RBSH;
            int pos = atomicAdd(&lbase[b], 1);
            if (pos < cap)
                bbuf[(size_t)b * cap + pos] = ((unsigned)(u & (RB - 1)) << 17) | (unsigned)c;
            else { int o = atomicAdd(ovfc, 1); if (o < ovf_cap) ovf[o] = make_int2(u, c); }
            b = c >> RBSH;
            pos = atomicAdd(&lbase[b], 1);
            if (pos < cap)
                bbuf[(size_t)b * cap + pos] = ((unsigned)(c & (RB - 1)) << 17) | (unsigned)u;
            else { int o = atomicAdd(ovfc, 1); if (o < ovf_cap) ovf[o] = make_int2(c, u); }
        }
    }
}

// ---------- phase 2: per-bucket LDS-staged ELL + dinv + fused y0 (fp8) ------
// ELL table for the 128-row bucket lives in LDS (32KB): records placed via
// LDS atomic + ds_write (zero-init supplies the pad), then streamed out as
// coalesced uint4 -- no uncoalesced global writes.
__global__ void __launch_bounds__(1024)
build_k(const unsigned int* __restrict__ bbuf, const int* __restrict__ gcur,
        int* __restrict__ cnt, int* __restrict__ colE, float* __restrict__ dinv,
        const float* __restrict__ ue, const float* __restrict__ ie,
        unsigned char* __restrict__ y0,
        int2* __restrict__ rovf, int* __restrict__ rovfc,
        int N, int U, int cap, int rovf_cap) {
    __shared__ int lcnt[RB];
    __shared__ float ldv[RB];
    __shared__ int ell[RB * ELLC];   // 32KB
    int b = blockIdx.x;
    for (int i = threadIdx.x; i < RB; i += blockDim.x) lcnt[i] = 0;
    for (int i = threadIdx.x; i < RB * ELLC; i += blockDim.x) ell[i] = 0;
    __syncthreads();
    int nb = min(gcur[b], cap);
    const unsigned int* src = bbuf + (size_t)b * cap;
    for (int e = threadIdx.x; e < nb; e += blockDim.x) {
        unsigned w = src[e];
        int r7 = (int)(w >> 17);
        int c = (int)(w & 0x1FFFF);
        int pos = atomicAdd(&lcnt[r7], 1);
        if (pos < ELLC) ell[(r7 << 6) + pos] = c;
        else {
            int o = atomicAdd(rovfc, 1);
            if (o < rovf_cap) rovf[o] = make_int2((b << RBSH) + r7, c);
        }
    }
    __syncthreads();
    for (int i = threadIdx.x; i < RB; i += blockDim.x) {
        int r = (b << RBSH) + i;
        if (r < N) {
            int d = lcnt[i];
            cnt[r] = d;
            float dv = (d > 0) ? rsqrtf((float)d) : 0.0f;
            dinv[r] = dv;            // spill rows fixed in fix_k
            ldv[i] = dv;
        }
    }
    __syncthreads();
    int r0 = b << RBSH;
    int rows = min(RB, N - r0);
    // fused y0 = fp8(SC0 * dinv * e0) for this bucket's rows (coalesced uint)
    for (int w = threadIdx.x; w < rows * 16; w += blockDim.x) {
        int i = w >> 4, j = w & 15;         // word j covers dims 4j..4j+3
        int r = r0 + i;
        const float* s = (r < U) ? (ue + (size_t)r * LAT) : (ie + (size_t)(r - U) * LAT);
        float4 f = ((const float4*)s)[j];
        float sc = SC0 * ldv[i];
        int p = __builtin_amdgcn_cvt_pk_fp8_f32(sc * f.x, sc * f.y, 0, false);
        p = __builtin_amdgcn_cvt_pk_fp8_f32(sc * f.z, sc * f.w, p, true);
        ((unsigned*)y0)[(size_t)r * 16 + j] = (unsigned)p;
    }
    // coalesced ELL writeout: rows*64 ints = rows*16 uint4 (pad included)
    uint4* dst = (uint4*)(colE + (size_t)r0 * ELLC);
    const uint4* lsrc = (const uint4*)ell;
    for (int w = threadIdx.x; w < rows * 16; w += blockDim.x)
        dst[w] = lsrc[w];
}

// bin-phase spill fix-up + dinv + y0 repair (expected ~0 entries). Single
// block; __syncthreads between phases so final cnt is seen.
__global__ void __launch_bounds__(1024)
fix_k(const int2* __restrict__ ovf, const int* __restrict__ ovfc,
      int* __restrict__ cnt, int* __restrict__ colE, float* __restrict__ dinv,
      const float* __restrict__ ue, const float* __restrict__ ie,
      unsigned char* __restrict__ y0,
      int2* __restrict__ rovf, int* __restrict__ rovfc,
      int ovf_cap, int rovf_cap, int U) {
    int n = min(*ovfc, ovf_cap);
    for (int i = threadIdx.x; i < n; i += blockDim.x) {
        int r = ovf[i].x, c = ovf[i].y;
        int pos = atomicAdd(&cnt[r], 1);
        if (pos < ELLC) colE[(size_t)r * ELLC + pos] = c;
        else { int o = atomicAdd(rovfc, 1); if (o < rovf_cap) rovf[o] = make_int2(r, c); }
    }
    __syncthreads();
    for (int i = threadIdx.x; i < n; i += blockDim.x) {
        int r = ovf[i].x;
        int d = cnt[r];
        dinv[r] = (d > 0) ? rsqrtf((float)d) : 0.0f;
    }
    __syncthreads();
    for (int w = threadIdx.x; w < n * 16; w += blockDim.x) {
        int o = w >> 4, j = w & 15;
        int r = ovf[o].x;
        const float* s = (r < U) ? (ue + (size_t)r * LAT) : (ie + (size_t)(r - U) * LAT);
        float4 f = ((const float4*)s)[j];
        float sc = SC0 * dinv[r];
        int p = __builtin_amdgcn_cvt_pk_fp8_f32(sc * f.x, sc * f.y, 0, false);
        p = __builtin_amdgcn_cvt_pk_fp8_f32(sc * f.z, sc * f.w, p, true);
        ((unsigned*)y0)[(size_t)r * 16 + j] = (unsigned)p;
    }
}

// ---------- propagation core ----------
// unpack one fp8 dword into 2 f32x2 accumulators (v_pk_add_f32 adds)
__device__ __forceinline__ void acc_word(unsigned w, f32x2* a) {
    a[0] += __builtin_amdgcn_cvt_pk_f32_fp8((int)w, false);
    a[1] += __builtin_amdgcn_cvt_pk_f32_fp8((int)w, true);
}

// Row waves: 4 nodes/wave, one per 16-lane group. Lane decomposition within
// group: q = (lane>>2)&3 = neighbor slot (4 in flight), s4 = lane&3 = 16B
// chunk (dims 16*s4..16*s4+15). Cols preloaded TRANSPOSED: lane gl holds
// cols {gl, gl+16, gl+32, gl+48} -> step s (neighbors 4s..4s+3) needs one
// shfl from lane 4*(s&3)+q, compile-time component s>>2.
// Accumulators: f32x2 acc[8]; acc[i] = dims {16*s4+2i, 16*s4+2i+1} partials.
// Waves [NW, NW+2B): query gather (first: qacc = e0 exact fp32; else += x_k).
__global__ void __launch_bounds__(256, 4)
prop_h_k(const int* __restrict__ cnt, const int* __restrict__ colE,
         const float* __restrict__ dinv, const unsigned char* __restrict__ yin,
         unsigned char* __restrict__ yout,
         const int* __restrict__ users, const int* __restrict__ items,
         float* __restrict__ qacc,
         const float* __restrict__ ue, const float* __restrict__ ie,
         const int2* __restrict__ rovf, const int* __restrict__ rovfc,
         int rovf_cap, int B, int U, int first, int N, float inv_sin) {
    int wave = blockIdx.x * (blockDim.x >> 6) + (threadIdx.x >> 6);
    int lane = threadIdx.x & 63;
    int NW = (N + 3) >> 2;
    if (wave >= NW) {
        int qw = wave - NW;
        if (qw >= 2 * B) return;
        int node = (qw < B) ? users[qw] : (items[qw - B] + U);
        if (first) {
            float v = (node < U) ? ue[(size_t)node * LAT + lane]
                                 : ie[(size_t)(node - U) * LAT + lane];
            qacc[qw * LAT + lane] = v;
        } else {
            float di = dinv[node];
            unsigned bb = yin[(size_t)node * LAT + lane];      // one 64B line/wave
            f32x2 yv = __builtin_amdgcn_cvt_pk_f32_fp8((int)bb, false);
            qacc[qw * LAT + lane] += (di > 0.0f) ? yv[0] * inv_sin / di : 0.0f;
        }
        return;
    }
    int grp  = lane >> 4;          // group 0..3 -> node
    int gbase = lane & 48;         // grp*16
    int q  = (lane >> 2) & 3;      // neighbor slot within step
    int s4 = lane & 3;             // 16B chunk: dims 16*s4..16*s4+15
    int node = (wave << 2) + grp;
    int nadr = min(node, N - 1);   // clamped address for tail groups
    int len = (node < N) ? min(cnt[nadr], ELLC) : 0;
    const int* cp = colE + (size_t)nadr * ELLC;
    // transposed col registers: lane gl holds cols gl+16c (4 coalesced loads)
    int gl = lane & 15;
    int ca0 = cp[gl], ca1 = cp[16 + gl], ca2 = cp[32 + gl], ca3 = cp[48 + gl];
    // wave-uniform step bound (max len over the 4 groups)
    int wmax = len;
    wmax = max(wmax, __shfl_xor(wmax, 16));
    wmax = max(wmax, __shfl_xor(wmax, 32));
    wmax = __builtin_amdgcn_readfirstlane(wmax);
    const uint4* y16 = (const uint4*)yin;

    f32x2 acc[8];
#pragma unroll
    for (int j = 0; j < 8; ++j) acc[j] = (f32x2)(0.f);

#pragma unroll
    for (int c = 0; c < 4; ++c) {
        int cac = (c == 0) ? ca0 : (c == 1) ? ca1 : (c == 2) ? ca2 : ca3;
#pragma unroll
        for (int si = 0; si < 4; ++si) {
            int s = (c << 2) + si;
            if ((s << 2) < wmax) {                 // wave-uniform guard
                int col = __shfl(cac, gbase + (si << 2) + q);   // 1 shfl / 4 nbrs
                if ((s << 2) + q < len) {          // per-lane validity
                    uint4 v = y16[(size_t)col * 4 + s4];
                    acc_word(v.x, acc + 0); acc_word(v.y, acc + 2);
                    acc_word(v.z, acc + 4); acc_word(v.w, acc + 6);
                }
            }
        }
    }
    // inline overflow epilogue (rovf static across layers; expected ~0):
    // q==0 lanes (s4 = 0..3) cover the full row; reduce sums it in.
    int novf = min(*rovfc, rovf_cap);
    for (int o = 0; o < novf; ++o) {
        int2 eo = rovf[o];
        if (eo.x == node && q == 0) {
            uint4 vv = y16[(size_t)eo.y * 4 + s4];
            acc_word(vv.x, acc + 0); acc_word(vv.y, acc + 2);
            acc_word(vv.z, acc + 4); acc_word(vv.w, acc + 6);
        }
    }
    // reduce-scatter across q (12 shfl, vector adds): stage A xor4 (q bit0),
    // keep 8 dims (acc[0..3] vs acc[4..7]); stage B xor8 (q bit1), keep 4
    // (acc[0..1] vs acc[2..3]). Lane ends with dims d0..d0+3 fully summed,
    // d0 = 16*s4 + 8*b2 + 4*b3.
    {
        bool hi = (lane & 4) != 0;
        f32x2 s[4], k[4];
#pragma unroll
        for (int i = 0; i < 4; ++i) { k[i] = hi ? acc[4 + i] : acc[i]; s[i] = hi ? acc[i] : acc[4 + i]; }
#pragma unroll
        for (int i = 0; i < 4; ++i) {
            f32x2 t;
            t.x = __shfl_xor(s[i].x, 4);
            t.y = __shfl_xor(s[i].y, 4);
            acc[i] = k[i] + t;
        }
    }
    {
        bool hi = (lane & 8) != 0;
        f32x2 s[2], k[2];
#pragma unroll
        for (int i = 0; i < 2; ++i) { k[i] = hi ? acc[2 + i] : acc[i]; s[i] = hi ? acc[i] : acc[2 + i]; }
#pragma unroll
        for (int i = 0; i < 2; ++i) {
            f32x2 t;
            t.x = __shfl_xor(s[i].x, 8);
            t.y = __shfl_xor(s[i].y, 8);
            acc[i] = k[i] + t;
        }
    }
    // zero-shuffle pack + store: lane packs its 4 dims into 1 dword; 64 lanes
    // store 4 nodes x 64B coalesced.
    float dv = dinv[nadr];
    float f = dv * dv * RSC;               // fold out/in scale ratio into dinv^2
    int pk = __builtin_amdgcn_cvt_pk_fp8_f32(f * acc[0].x, f * acc[0].y, 0, false);
    pk = __builtin_amdgcn_cvt_pk_fp8_f32(f * acc[1].x, f * acc[1].y, pk, true);
    if (node < N) {
        int b2 = (lane >> 2) & 1, b3 = (lane >> 3) & 1;
        ((unsigned*)yout)[(size_t)node * 16 + (s4 << 2) + (b2 << 1) + b3] = (unsigned)pk;
    }
}

// final: qacc += x4 at queried nodes, then gamma = dot/25 (fused last qgather)
__global__ void final_k(const float* __restrict__ qacc, const unsigned char* __restrict__ y4,
                        const float* __restrict__ dinv,
                        const int* __restrict__ users, const int* __restrict__ items,
                        float* __restrict__ out, int B, int U, float inv_s4) {
    int wave = blockIdx.x * (blockDim.x >> 6) + (threadIdx.x >> 6);
    int lane = threadIdx.x & 63;
    if (wave >= B) return;
    int un = users[wave];
    int in = items[wave] + U;
    float du = dinv[un], di = dinv[in];
    unsigned bu = y4[(size_t)un * LAT + lane];
    unsigned bi = y4[(size_t)in * LAT + lane];
    f32x2 xuv = __builtin_amdgcn_cvt_pk_f32_fp8((int)bu, false);
    f32x2 xiv = __builtin_amdgcn_cvt_pk_f32_fp8((int)bi, false);
    float au = qacc[wave * LAT + lane]       + ((du > 0.f) ? xuv[0] * inv_s4 / du : 0.f);
    float ai = qacc[(wave + B) * LAT + lane] + ((di > 0.f) ? xiv[0] * inv_s4 / di : 0.f);
    float p = au * ai;
#pragma unroll
    for (int off = 32; off > 0; off >>= 1) p += __shfl_down(p, off);
    if (lane == 0) out[wave] = p * (1.0f / 25.0f);
}

extern "C" void kernel_launch(void* const* d_in, const int* in_sizes, int n_in,
                              void* d_out, int out_size, void* d_ws, size_t ws_size,
                              hipStream_t stream) {
    const float* ue = (const float*)d_in[0];
    const float* ie = (const float*)d_in[1];
    const int* edge = (const int*)d_in[2];
    const int* users = (const int*)d_in[3];
    const int* items = (const int*)d_in[4];

    const int U = in_sizes[0] / LAT;
    const int I = in_sizes[1] / LAT;
    const int N = U + I;
    const int E = in_sizes[2] / 2;
    const int B = in_sizes[3];
    const int* eu = edge;
    const int* ei = edge + E;

    const int nbuk = (N + RB - 1) / RB;                    // 782 for N=100k
    const int cap = ((2 * E / nbuk) * 5 / 4 + 255) & ~255; // ~25% slack

    char* ws = (char*)d_ws;
    size_t off = 0;
    auto alloc = [&](size_t bytes) -> void* {
        void* p = ws + off;
        off += (bytes + 255) & ~(size_t)255;
        return p;
    };
    int*           cnt  = (int*)alloc((size_t)4 * N);
    float*         dinv = (float*)alloc((size_t)4 * N);
    int*           colE = (int*)alloc((size_t)4 * N * ELLC);     // 25.6 MB
    unsigned char* yA   = (unsigned char*)alloc((size_t)N * LAT); // 6.4 MB fp8
    unsigned char* yB   = (unsigned char*)alloc((size_t)N * LAT);
    float*         qacc = (float*)alloc((size_t)4 * 2 * B * LAT);
    unsigned*      bbuf = (unsigned*)alloc((size_t)4 * nbuk * cap);  // ~16 MB
    // gcur and ovfc adjacent -> single memset covers both
    size_t zoff = off;
    int*      gcur = (int*)alloc((size_t)4 * nbuk);
    int*      ovfc = (int*)alloc(256);   // 64 ints: [0]=bin spill, [16]=row ovf
    size_t zbytes = off - zoff;
    size_t remain = (ws_size > off + 256) ? (ws_size - off - 256) : 0;
    int ovf_cap = (int)min((size_t)131072, remain / (2 * sizeof(int2)));
    int2* ovf  = (int2*)alloc((size_t)ovf_cap * sizeof(int2));
    int2* rovf = (int2*)alloc((size_t)ovf_cap * sizeof(int2));
    // rovfc = ovfc + 16 INTS (byte 64): stays inside the zeroed 256-byte
    // block. (ovfc + 64 was byte 256 = ovf[0] -- the R7 34.7ms bug.)
    int* rovfc = ovfc + 16;

    hipError_t _e = hipMemsetAsync(gcur, 0, zbytes, stream); (void)_e;

    const int tb = 256;

    // 256 blocks x 1024 thr x RPT 8 = 2.1M >= E undirected edges
    bin_k<<<256, 1024, 0, stream>>>(eu, ei, gcur, bbuf, ovf, ovfc, E, U, nbuk, cap, ovf_cap);
    build_k<<<nbuk, 1024, 0, stream>>>(bbuf, gcur, cnt, colE, dinv, ue, ie, yA,
                                       rovf, rovfc, N, U, cap, ovf_cap);
    fix_k<<<1, 1024, 0, stream>>>(ovf, ovfc, cnt, colE, dinv, ue, ie, yA,
                                  rovf, rovfc, ovf_cap, ovf_cap, U);

    const int wpb = tb / 64;
    const int NW = (N + 3) >> 2;               // 4 nodes per row-wave
    int pgrid = (NW + 2 * B + wpb - 1) / wpb;  // row waves + fused query waves

    unsigned char* yin = yA;
    unsigned char* yout = yB;
    float s_in = SC0;
    for (int layer = 0; layer < 4; ++layer) {
        prop_h_k<<<pgrid, tb, 0, stream>>>(cnt, colE, dinv, yin, yout,
                                           users, items, qacc, ue, ie, rovf, rovfc,
                                           ovf_cap, B, U, layer == 0 ? 1 : 0, N,
                                           1.0f / s_in);
        s_in *= RSC;
        unsigned char* tmp = yin; yin = yout; yout = tmp;
    }

    final_k<<<(B + wpb - 1) / wpb, tb, 0, stream>>>(qacc, yin, dinv, users, items,
                                                    (float*)d_out, B, U, 1.0f / s_in);
}